// Round 17
// baseline (38.901 us; speedup 1.0000x reference)
//
#include <hip/hip_runtime.h>
#include <math.h>

#define G     1000
#define B     32
#define NC    2048
#define NT    2048
#define BN    (B * NT)
#define LOG2E 1.4426950408889634f
#define LN2PI 1.8378770664093453f   // ln(2*pi)

#if __has_builtin(__builtin_amdgcn_exp2f)
#define EXP2F(x) __builtin_amdgcn_exp2f(x)
#else
#define EXP2F(x) exp2f(x)
#endif

typedef float f32x2 __attribute__((ext_vector_type(2)));
#define PKFMA(a, b, c) __builtin_elementwise_fma(a, b, c)
#define PKMAX(a, b)    __builtin_elementwise_max(a, b)
#define SPLAT_LO(v)    __builtin_shufflevector(v, v, 0, 0)
#define SPLAT_HI(v)    __builtin_shufflevector(v, v, 1, 1)

static __device__ __forceinline__ f32x2 splat2(float x) {
  f32x2 r = {x, x};
  return r;
}

// ---------------------------------------------------------------------------
// Kernel A v7 (frozen): packed-f32 Gaussian recurrence along g.
// ---------------------------------------------------------------------------
__global__ __launch_bounds__(512) void k_smooth(
    const float* __restrict__ xc, const float* __restrict__ yc,
    const float* __restrict__ ls_x, float* __restrict__ h,
    float* __restrict__ loss_slot) {
  __shared__ float2 sxy[NC];              // {s*x_n, y_n}, 16KB
  __shared__ float2 part[8][64];          // per-wave {h0,h1} partials, 4KB
  if (blockIdx.x == 0 && blockIdx.y == 0 && threadIdx.x == 0) *loss_slot = 0.f;

  int tid = threadIdx.x;
  int b = blockIdx.y, tile = blockIdx.x;
  float ls  = ls_x[0];
  float s   = sqrtf(0.5f * LOG2E) / ls;   // w = exp2(-(s*t - s*x)^2)
  float dlt = s * (4.4f / 999.f);

  const float* xb = xc + b * NC;
  const float* yb = yc + b * NC;
  for (int n = tid; n < NC; n += 512) sxy[n] = make_float2(s * xb[n], yb[n]);
  __syncthreads();

  int lane = tid & 63, w = tid >> 6;      // w = n-slice (256 n)
  int ns = lane & 7, gr = lane >> 3;      // 8 n-subs x 8 g-runs (8 g each)
  int g0 = tile * 64 + gr * 8;
  float v0 = s * -2.2f + dlt * (float)g0; // s*t at g0
  float r  = EXP2F(-2.f * dlt * dlt);
  float r3 = r * r * r;
  float r4 = r3 * r;
  const f32x2 R4 = {r4, r4};

  f32x2 h0p[4], h1p[4];
  #pragma unroll
  for (int j = 0; j < 4; ++j) { h0p[j] = (f32x2)0.f; h1p[j] = (f32x2)0.f; }

  const float2* base = sxy + w * 256 + ns;
  #pragma unroll 4
  for (int i = 0; i < 32; ++i) {
    float2 v = base[i * 8];
    float a  = v.x - v0;
    float W0 = EXP2F(64.f - a * a);
    float q  = EXP2F(fmaf(2.f * dlt, a, -dlt * dlt));
    float qq = q * q;
    f32x2 W2 = {W0, W0 * q};
    f32x2 S2 = {qq * r, qq * r3};
    f32x2 y2 = splat2(v.y);
    #pragma unroll
    for (int j = 0; j < 4; ++j) {
      h0p[j] += W2;
      h1p[j] = PKFMA(W2, y2, h1p[j]);
      W2 *= S2;
      S2 *= R4;
    }
  }
  #pragma unroll
  for (int m = 1; m < 8; m <<= 1) {
    #pragma unroll
    for (int j = 0; j < 4; ++j) {
      h0p[j].x += __shfl_xor(h0p[j].x, m);
      h0p[j].y += __shfl_xor(h0p[j].y, m);
      h1p[j].x += __shfl_xor(h1p[j].x, m);
      h1p[j].y += __shfl_xor(h1p[j].y, m);
    }
  }
  #pragma unroll
  for (int j = 0; j < 4; ++j) {
    if (ns == j) {
      part[w][gr * 8 + 2 * j]     = make_float2(h0p[j].x, h1p[j].x);
      part[w][gr * 8 + 2 * j + 1] = make_float2(h0p[j].y, h1p[j].y);
    }
  }
  __syncthreads();

  if (tid < 64) {
    int g = tile * 64 + tid;
    if (g < G) {
      float d0 = 0.f, d1 = 0.f;
      #pragma unroll
      for (int k = 0; k < 8; ++k) { float2 pv = part[k][tid]; d0 += pv.x; d1 += pv.y; }
      d0 *= 0x1p-64f;
      d1 *= 0x1p-64f;
      h[(b * 2 + 0) * G + g] = d0;
      h[(b * 2 + 1) * G + g] = d1 / (d0 + 1e-8f);
    }
  }
}

// ---------------------------------------------------------------------------
// Kernel B v9: packed-f32 across OUTPUT-CHANNEL PAIRS (keeps 256 threads).
// L2: 16 pairs x 16 subs (POS=4) = 256 thr, 20 pk_fma/ic (was 40 scalar).
// L3: 8 pairs -> ic-split on lane bit 5, shfl_xor(32) epilogue = 256 thr.
// L1/L4 scalar (tiny). TILE=48, CSTR=68; valid chain as v8.
// ---------------------------------------------------------------------------
#define TILE  48
#define NTILE 21   // 21*48 = 1008 >= 1000
#define CSTR  68

__device__ __forceinline__ void conv4_l1(
    const float* __restrict__ in, float* __restrict__ out,
    const float4* __restrict__ wf4, const float* __restrict__ w4p,
    const float* __restrict__ bias, int tid) {
  int oc = tid & 15;
  int i0 = (tid >> 4) * 4;                // 0..60
  float acc[4];
  float bb = bias[oc];
  #pragma unroll
  for (int p = 0; p < 4; ++p) acc[p] = bb;
  #pragma unroll
  for (int ic = 0; ic < 2; ++ic) {
    const float4* ip = (const float4*)(in + ic * CSTR + i0);
    float4 A = ip[0], Bv = ip[1];
    float v[8] = {A.x, A.y, A.z, A.w, Bv.x, Bv.y, Bv.z, Bv.w};
    float4 w = wf4[oc * 3 + ic];
    float w4v = w4p[ic * 16 + oc];
    #pragma unroll
    for (int p = 0; p < 4; ++p)
      acc[p] = fmaf(v[p], w.x, fmaf(v[p+1], w.y, fmaf(v[p+2], w.z,
               fmaf(v[p+3], w.w, fmaf(v[p+4], w4v, acc[p])))));
  }
  float* op = out + oc * CSTR + i0 + 2;
  *(float2*)op       = make_float2(fmaxf(acc[0], 0.f), fmaxf(acc[1], 0.f));
  *(float2*)(op + 2) = make_float2(fmaxf(acc[2], 0.f), fmaxf(acc[3], 0.f));
}

__device__ __forceinline__ void conv_pk_l2(
    const float* __restrict__ in, float* __restrict__ out,
    const f32x2* __restrict__ wpk, const float* __restrict__ bias, int tid) {
  int lane = tid & 63, w = tid >> 6;
  int pair = lane & 15, subL = lane >> 4;
  int i0 = (w * 4 + subL) * 4;            // 0..60
  int oc0 = pair * 2;
  f32x2 bb = {bias[oc0], bias[oc0 + 1]};
  f32x2 acc2[4];
  #pragma unroll
  for (int p = 0; p < 4; ++p) acc2[p] = bb;
  #pragma unroll 4
  for (int ic = 0; ic < 16; ++ic) {
    const float4* ip = (const float4*)(in + ic * CSTR + i0);
    float4 A = ip[0], Bv = ip[1];
    float v[8] = {A.x, A.y, A.z, A.w, Bv.x, Bv.y, Bv.z, Bv.w};
    const f32x2* wp = wpk + pair * 81 + ic * 5;
    f32x2 w0 = wp[0], w1 = wp[1], w2 = wp[2], w3 = wp[3], w4 = wp[4];
    #pragma unroll
    for (int p = 0; p < 4; ++p) {
      acc2[p] = PKFMA(w0, splat2(v[p]),   acc2[p]);
      acc2[p] = PKFMA(w1, splat2(v[p+1]), acc2[p]);
      acc2[p] = PKFMA(w2, splat2(v[p+2]), acc2[p]);
      acc2[p] = PKFMA(w3, splat2(v[p+3]), acc2[p]);
      acc2[p] = PKFMA(w4, splat2(v[p+4]), acc2[p]);
    }
  }
  #pragma unroll
  for (int p = 0; p < 4; ++p) acc2[p] = PKMAX(acc2[p], (f32x2)0.f);
  float* o0 = out + oc0 * CSTR + i0 + 2;
  float* o1 = o0 + CSTR;
  *(float2*)o0       = make_float2(acc2[0].x, acc2[1].x);
  *(float2*)(o0 + 2) = make_float2(acc2[2].x, acc2[3].x);
  *(float2*)o1       = make_float2(acc2[0].y, acc2[1].y);
  *(float2*)(o1 + 2) = make_float2(acc2[2].y, acc2[3].y);
}

__device__ __forceinline__ void conv_pk_l3(
    const float* __restrict__ in, float* __restrict__ out,
    const f32x2* __restrict__ wpk, const float* __restrict__ bias, int tid) {
  int lane = tid & 63, w = tid >> 6;
  int ichalf = lane >> 5;                 // 0/1
  int pair   = (lane >> 2) & 7;           // 0..7
  int subL   = lane & 3;
  int i0 = (w * 4 + subL) * 4;            // 0..60
  int icb = ichalf * 16;
  f32x2 acc2[4];
  #pragma unroll
  for (int p = 0; p < 4; ++p) acc2[p] = (f32x2)0.f;
  #pragma unroll 4
  for (int j = 0; j < 16; ++j) {
    int ic = icb + j;
    const float4* ip = (const float4*)(in + ic * CSTR + i0);
    float4 A = ip[0], Bv = ip[1];
    float v[8] = {A.x, A.y, A.z, A.w, Bv.x, Bv.y, Bv.z, Bv.w};
    const f32x2* wp = wpk + pair * 161 + ic * 5;
    f32x2 w0 = wp[0], w1 = wp[1], w2 = wp[2], w3 = wp[3], w4 = wp[4];
    #pragma unroll
    for (int p = 0; p < 4; ++p) {
      acc2[p] = PKFMA(w0, splat2(v[p]),   acc2[p]);
      acc2[p] = PKFMA(w1, splat2(v[p+1]), acc2[p]);
      acc2[p] = PKFMA(w2, splat2(v[p+2]), acc2[p]);
      acc2[p] = PKFMA(w3, splat2(v[p+3]), acc2[p]);
      acc2[p] = PKFMA(w4, splat2(v[p+4]), acc2[p]);
    }
  }
  // combine ic-halves (partner = lane ^ 32, same wave)
  #pragma unroll
  for (int p = 0; p < 4; ++p) {
    acc2[p].x += __shfl_xor(acc2[p].x, 32);
    acc2[p].y += __shfl_xor(acc2[p].y, 32);
  }
  if (ichalf == 0) {
    int oc0 = pair * 2;
    f32x2 bb = {bias[oc0], bias[oc0 + 1]};
    #pragma unroll
    for (int p = 0; p < 4; ++p) acc2[p] = PKMAX(acc2[p] + bb, (f32x2)0.f);
    float* o0 = out + oc0 * CSTR + i0 + 2;
    float* o1 = o0 + CSTR;
    *(float2*)o0       = make_float2(acc2[0].x, acc2[1].x);
    *(float2*)(o0 + 2) = make_float2(acc2[2].x, acc2[3].x);
    *(float2*)o1       = make_float2(acc2[0].y, acc2[1].y);
    *(float2*)(o1 + 2) = make_float2(acc2[2].y, acc2[3].y);
  }
}

__global__ __launch_bounds__(256, 2) void k_conv(
    const float* __restrict__ h,
    const float* __restrict__ W1, const float* __restrict__ Bs1,
    const float* __restrict__ W2, const float* __restrict__ Bs2,
    const float* __restrict__ W3, const float* __restrict__ Bs3,
    const float* __restrict__ W4, const float* __restrict__ Bs4,
    float* __restrict__ yg) {
  __shared__ __align__(16) float bufA[32 * CSTR], bufB[32 * CSTR];
  __shared__ float4 wf1[16 * 3];
  __shared__ float  w41[2 * 16];
  __shared__ f32x2  wp2[16 * 81];         // [pair][ic*5+k], stride 81
  __shared__ f32x2  wp3[8 * 161];         // [pair][ic*5+k], stride 161
  __shared__ float  wt4[162];
  __shared__ float  sB1[16], sB2[32], sB3[16], sB4[2];

  int tid  = threadIdx.x;
  int tile = blockIdx.x, b = blockIdx.y;
  int ts   = tile * TILE;

  if (tid < 32) {                         // L1: oc<16, ic<2
    int oc = tid >> 1, ic = tid & 1, a = oc * 10 + ic * 5;
    wf1[oc * 3 + ic] = make_float4(W1[a], W1[a+1], W1[a+2], W1[a+3]);
    w41[ic * 16 + oc] = W1[a + 4];
  }
  for (int i = tid; i < 1280; i += 256) { // L2 pairs: rem = ic*5+k
    int pair = i / 80, rem = i - pair * 80;
    f32x2 t = {W2[(2*pair)*80 + rem], W2[(2*pair+1)*80 + rem]};
    wp2[pair * 81 + rem] = t;
  }
  for (int i = tid; i < 1280; i += 256) { // L3 pairs
    int pair = i / 160, rem = i - pair * 160;
    f32x2 t = {W3[(2*pair)*160 + rem], W3[(2*pair+1)*160 + rem]};
    wp3[pair * 161 + rem] = t;
  }
  for (int i = tid; i < 160; i += 256) wt4[(i / 80) * 81 + i % 80] = W4[i];
  if (tid < 16)       sB1[tid]      = Bs1[tid];
  else if (tid < 48)  sB2[tid - 16] = Bs2[tid - 16];
  else if (tid < 64)  sB3[tid - 48] = Bs3[tid - 48];
  else if (tid < 66)  sB4[tid - 64] = Bs4[tid - 64];

  for (int i = tid; i < 2 * CSTR; i += 256) {
    int c = i >= CSTR, col = i - c * CSTR;
    int g = ts + col - 10;
    bufA[c * CSTR + col] = (g >= 0 && g < G) ? h[(b * 2 + c) * G + g] : 0.f;
  }
  __syncthreads();

  conv4_l1(bufA, bufB, wf1, w41, sB1, tid);            // 256 thr scalar
  __syncthreads();
  conv_pk_l2(bufB, bufA, wp2, sB2, tid);               // 256 thr packed
  __syncthreads();
  conv_pk_l3(bufA, bufB, wp3, sB3, tid);               // 256 thr packed+split
  __syncthreads();

  if (tid < 96) {                         // L4 scalar
    int oc = tid >= 48;
    int j  = tid - oc * 48;
    int i  = 10 + j;
    float sacc = sB4[oc];
    #pragma unroll
    for (int ic = 0; ic < 16; ++ic) {
      const float* ip = bufB + ic * CSTR + i - 2;
      #pragma unroll
      for (int k = 0; k < 5; ++k)
        sacc = fmaf(ip[k], wt4[oc * 81 + ic * 5 + k], sacc);
    }
    int gp = ts + j;
    if (gp < G) {
      if (oc == 0) {
        yg[(b * 2 + 0) * G + gp] = sacc;
      } else {
        float sp_ = fmaxf(sacc, 0.f) + log1pf(__expf(-fabsf(sacc)));
        yg[(b * 2 + 1) * G + gp] = sp_;
      }
    }
  }
}

// ---------------------------------------------------------------------------
// Kernel C v7 (frozen): packed-f32 Gaussian recurrence, 2 t/lane.
// ---------------------------------------------------------------------------
__global__ __launch_bounds__(512) void k_pred(
    const float* __restrict__ xt, const float* __restrict__ yt,
    const float* __restrict__ ls_rho, const float* __restrict__ yg,
    float* __restrict__ out) {
  __shared__ float4 sp[512];              // {y0[2j], y1[2j], y0[2j+1], y1[2j+1]}
  __shared__ float pA0[512], pA1[512], pB0[512], pB1[512];
  __shared__ float red[8];

  int tid = threadIdx.x;
  int b = blockIdx.y, tile = blockIdx.x;
  float ls = ls_rho[0];
  float s  = sqrtf(0.5f * LOG2E) / ls;
  float dl = s * (4.4f / 999.f);

  const float* y0 = yg + (b * 2 + 0) * G;
  const float* y1 = yg + (b * 2 + 1) * G;
  {
    int g0 = 2 * tid, g1 = 2 * tid + 1;
    float a0 = (g0 < G) ? y0[g0] : 0.f, b0_ = (g0 < G) ? y1[g0] : 0.f;
    float a1 = (g1 < G) ? y0[g1] : 0.f, b1_ = (g1 < G) ? y1[g1] : 0.f;
    sp[tid] = make_float4(a0, b0_, a1, b1_);
  }
  __syncthreads();

  int lane = tid & 63, wv = tid >> 6;     // wv = g-slice 0..7 (128 g each)
  int ta = tile * 128 + lane;
  float ua = s * xt[b * NT + ta];
  float ub = s * xt[b * NT + ta + 64];
  float base = 2.2f * s - dl * (float)(wv * 128);
  float aa = ua + base, ab = ub + base;
  float r = EXP2F(-2.f * dl * dl);
  f32x2 Wab = {EXP2F(64.f - aa * aa), EXP2F(64.f - ab * ab)};
  f32x2 qab = {EXP2F(dl * (aa + aa) - dl * dl), EXP2F(dl * (ab + ab) - dl * dl)};
  const f32x2 R2 = {r, r};

  f32x2 accA = (f32x2)0.f, accB = (f32x2)0.f;   // (mu, sg)
  const float4* p = sp + wv * 64;
  #pragma unroll 4
  for (int i = 0; i < 64; ++i) {
    float4 v = p[i];
    f32x2 v01 = {v.x, v.y};
    f32x2 v23 = {v.z, v.w};
    accA = PKFMA(SPLAT_LO(Wab), v01, accA);
    accB = PKFMA(SPLAT_HI(Wab), v01, accB);
    Wab *= qab; qab *= R2;
    accA = PKFMA(SPLAT_LO(Wab), v23, accA);
    accB = PKFMA(SPLAT_HI(Wab), v23, accB);
    Wab *= qab; qab *= R2;
  }
  pA0[tid] = accA.x; pA1[tid] = accA.y; pB0[tid] = accB.x; pB1[tid] = accB.y;
  __syncthreads();

  float lp = 0.f;
  if (tid < 128) {
    int which = tid >> 6, l = tid & 63;
    int t = tile * 128 + which * 64 + l;
    const float* q0 = which ? pB0 : pA0;
    const float* q1 = which ? pB1 : pA1;
    float mu = 0.f, sg = 0.f;
    #pragma unroll
    for (int k = 0; k < 8; ++k) { mu += q0[l + 64 * k]; sg += q1[l + 64 * k]; }
    mu *= 0x1p-64f;
    sg *= 0x1p-64f;
    out[b * NT + t]      = mu;
    out[BN + b * NT + t] = sg;
    float z = (yt[b * NT + t] - mu) / sg;
    lp = -0.5f * z * z - __logf(sg) - 0.5f * LN2PI;
  }
  #pragma unroll
  for (int m = 32; m; m >>= 1) lp += __shfl_xor(lp, m);
  if ((tid & 63) == 0) red[tid >> 6] = lp;
  __syncthreads();
  if (tid == 0) {
    float tot = 0.f;
    #pragma unroll
    for (int i = 0; i < 8; ++i) tot += red[i];
    atomicAdd(out + 2 * BN, -tot * (1.f / (float)NT));
  }
}

extern "C" void kernel_launch(void* const* d_in, const int* in_sizes, int n_in,
                              void* d_out, int out_size, void* d_ws, size_t ws_size,
                              hipStream_t stream) {
  const float* xc  = (const float*)d_in[0];
  const float* yc  = (const float*)d_in[1];
  const float* xt  = (const float*)d_in[2];
  const float* yt  = (const float*)d_in[3];
  const float* lsx = (const float*)d_in[4];
  const float* lsr = (const float*)d_in[5];
  const float* W1  = (const float*)d_in[6];  const float* b1 = (const float*)d_in[7];
  const float* W2  = (const float*)d_in[8];  const float* b2 = (const float*)d_in[9];
  const float* W3  = (const float*)d_in[10]; const float* b3 = (const float*)d_in[11];
  const float* W4  = (const float*)d_in[12]; const float* b4 = (const float*)d_in[13];

  float* out = (float*)d_out;
  float* h   = (float*)d_ws;        // B*2*G
  float* yg  = h + B * 2 * G;       // B*2*G

  k_smooth<<<dim3(16, B), 512, 0, stream>>>(xc, yc, lsx, h, out + 2 * BN);
  k_conv<<<dim3(NTILE, B), 256, 0, stream>>>(h, W1, b1, W2, b2, W3, b3, W4, b4, yg);
  k_pred<<<dim3(16, B), 512, 0, stream>>>(xt, yt, lsr, yg, out);
}

// Round 18
// 37.189 us; speedup vs baseline: 1.0460x; 1.0460x over previous
//
#include <hip/hip_runtime.h>
#include <math.h>

#define G     1000
#define B     32
#define NC    2048
#define NT    2048
#define BN    (B * NT)
#define LOG2E 1.4426950408889634f
#define LN2PI 1.8378770664093453f   // ln(2*pi)

#if __has_builtin(__builtin_amdgcn_exp2f)
#define EXP2F(x) __builtin_amdgcn_exp2f(x)
#else
#define EXP2F(x) exp2f(x)
#endif

typedef float f32x2 __attribute__((ext_vector_type(2)));
#define PKFMA(a, b, c) __builtin_elementwise_fma(a, b, c)
#define SPLAT_LO(v)    __builtin_shufflevector(v, v, 0, 0)
#define SPLAT_HI(v)    __builtin_shufflevector(v, v, 1, 1)

// ---------------------------------------------------------------------------
// Kernel A v7 (r15 best): packed-f32 Gaussian recurrence along g.
// Grid (16, B) = 512 blocks = 2/CU; lane owns 8 g (4 pairs) + 32 strided n.
// ---------------------------------------------------------------------------
__global__ __launch_bounds__(512) void k_smooth(
    const float* __restrict__ xc, const float* __restrict__ yc,
    const float* __restrict__ ls_x, float* __restrict__ h,
    float* __restrict__ loss_slot) {
  __shared__ float2 sxy[NC];              // {s*x_n, y_n}, 16KB
  __shared__ float2 part[8][64];          // per-wave {h0,h1} partials, 4KB
  if (blockIdx.x == 0 && blockIdx.y == 0 && threadIdx.x == 0) *loss_slot = 0.f;

  int tid = threadIdx.x;
  int b = blockIdx.y, tile = blockIdx.x;
  float ls  = ls_x[0];
  float s   = sqrtf(0.5f * LOG2E) / ls;   // w = exp2(-(s*t - s*x)^2)
  float dlt = s * (4.4f / 999.f);

  const float* xb = xc + b * NC;
  const float* yb = yc + b * NC;
  for (int n = tid; n < NC; n += 512) sxy[n] = make_float2(s * xb[n], yb[n]);
  __syncthreads();

  int lane = tid & 63, w = tid >> 6;      // w = n-slice (256 n)
  int ns = lane & 7, gr = lane >> 3;      // 8 n-subs x 8 g-runs (8 g each)
  int g0 = tile * 64 + gr * 8;
  float v0 = s * -2.2f + dlt * (float)g0; // s*t at g0
  float r  = EXP2F(-2.f * dlt * dlt);
  float r3 = r * r * r;
  float r4 = r3 * r;
  const f32x2 R4 = {r4, r4};

  f32x2 h0p[4], h1p[4];
  #pragma unroll
  for (int j = 0; j < 4; ++j) { h0p[j] = (f32x2)0.f; h1p[j] = (f32x2)0.f; }

  const float2* base = sxy + w * 256 + ns;
  #pragma unroll 4
  for (int i = 0; i < 32; ++i) {
    float2 v = base[i * 8];
    float a  = v.x - v0;
    float W0 = EXP2F(64.f - a * a);
    float q  = EXP2F(fmaf(2.f * dlt, a, -dlt * dlt));
    float qq = q * q;
    f32x2 W2 = {W0, W0 * q};
    f32x2 S2 = {qq * r, qq * r3};
    f32x2 y2 = {v.y, v.y};
    #pragma unroll
    for (int j = 0; j < 4; ++j) {
      h0p[j] += W2;
      h1p[j] = PKFMA(W2, y2, h1p[j]);
      W2 *= S2;
      S2 *= R4;
    }
  }
  #pragma unroll
  for (int m = 1; m < 8; m <<= 1) {
    #pragma unroll
    for (int j = 0; j < 4; ++j) {
      h0p[j].x += __shfl_xor(h0p[j].x, m);
      h0p[j].y += __shfl_xor(h0p[j].y, m);
      h1p[j].x += __shfl_xor(h1p[j].x, m);
      h1p[j].y += __shfl_xor(h1p[j].y, m);
    }
  }
  #pragma unroll
  for (int j = 0; j < 4; ++j) {
    if (ns == j) {
      part[w][gr * 8 + 2 * j]     = make_float2(h0p[j].x, h1p[j].x);
      part[w][gr * 8 + 2 * j + 1] = make_float2(h0p[j].y, h1p[j].y);
    }
  }
  __syncthreads();

  if (tid < 64) {
    int g = tile * 64 + tid;
    if (g < G) {
      float d0 = 0.f, d1 = 0.f;
      #pragma unroll
      for (int k = 0; k < 8; ++k) { float2 pv = part[k][tid]; d0 += pv.x; d1 += pv.y; }
      d0 *= 0x1p-64f;
      d1 *= 0x1p-64f;
      h[(b * 2 + 0) * G + g] = d0;
      h[(b * 2 + 1) * G + g] = d1 / (d0 + 1e-8f);
    }
  }
}

// ---------------------------------------------------------------------------
// Kernel B v8 (r15 best): full-occupancy mapping, scalar FMA (DS-pipe-bound;
// oc-pair packing regressed r17). L1/L3 POS=4 (256 thr), L2 POS=8 (256 thr).
// TILE=48, CSTR=68, grid (21 x B). Valid chain:
// L1 writes [2,66) -> L2 clean [4,64) -> L3 clean [6,62) -> L4 reads [8,60).
// ---------------------------------------------------------------------------
#define TILE  48
#define NTILE 21   // 21*48 = 1008 >= 1000
#define CSTR  68

template <int CIN, int COUT, int S4>
__device__ __forceinline__ void conv8(
    const float* __restrict__ in, float* __restrict__ out,
    const float4* __restrict__ wf4, const float* __restrict__ w4p,
    const float* __restrict__ bias, int tid) {
  if (tid < COUT * 8) {
    int oc = tid % COUT;
    int i0 = (tid / COUT) * 8;            // reads [i0,i0+12), writes [i0+2,i0+10)
    float acc[8];
    float bb = bias[oc];
    #pragma unroll
    for (int p = 0; p < 8; ++p) acc[p] = bb;
    for (int ic = 0; ic < CIN; ++ic) {
      const float4* ip = (const float4*)(in + ic * CSTR + i0);
      float4 A = ip[0], Bv = ip[1], C = ip[2];
      float v[12] = {A.x, A.y, A.z, A.w, Bv.x, Bv.y, Bv.z, Bv.w, C.x, C.y, C.z, C.w};
      float4 w = wf4[oc * S4 + ic];
      float w4v = w4p[ic * COUT + oc];
      #pragma unroll
      for (int p = 0; p < 8; ++p)
        acc[p] = fmaf(v[p], w.x, fmaf(v[p+1], w.y, fmaf(v[p+2], w.z,
                 fmaf(v[p+3], w.w, fmaf(v[p+4], w4v, acc[p])))));
    }
    float* op = out + oc * CSTR + i0 + 2;
    #pragma unroll
    for (int j = 0; j < 4; ++j)
      *(float2*)(op + 2 * j) = make_float2(fmaxf(acc[2*j], 0.f), fmaxf(acc[2*j+1], 0.f));
  }
}

template <int CIN, int COUT, int S4>
__device__ __forceinline__ void conv4(
    const float* __restrict__ in, float* __restrict__ out,
    const float4* __restrict__ wf4, const float* __restrict__ w4p,
    const float* __restrict__ bias, int tid) {
  int oc = tid % COUT;
  int i0 = (tid / COUT) * 4;              // 0..60
  float acc[4];
  float bb = bias[oc];
  #pragma unroll
  for (int p = 0; p < 4; ++p) acc[p] = bb;
  for (int ic = 0; ic < CIN; ++ic) {
    const float4* ip = (const float4*)(in + ic * CSTR + i0);
    float4 A = ip[0], Bv = ip[1];
    float v[8] = {A.x, A.y, A.z, A.w, Bv.x, Bv.y, Bv.z, Bv.w};
    float4 w = wf4[oc * S4 + ic];
    float w4v = w4p[ic * COUT + oc];
    #pragma unroll
    for (int p = 0; p < 4; ++p)
      acc[p] = fmaf(v[p], w.x, fmaf(v[p+1], w.y, fmaf(v[p+2], w.z,
               fmaf(v[p+3], w.w, fmaf(v[p+4], w4v, acc[p])))));
  }
  float* op = out + oc * CSTR + i0 + 2;
  *(float2*)op       = make_float2(fmaxf(acc[0], 0.f), fmaxf(acc[1], 0.f));
  *(float2*)(op + 2) = make_float2(fmaxf(acc[2], 0.f), fmaxf(acc[3], 0.f));
}

__global__ __launch_bounds__(256, 2) void k_conv(
    const float* __restrict__ h,
    const float* __restrict__ W1, const float* __restrict__ Bs1,
    const float* __restrict__ W2, const float* __restrict__ Bs2,
    const float* __restrict__ W3, const float* __restrict__ Bs3,
    const float* __restrict__ W4, const float* __restrict__ Bs4,
    float* __restrict__ yg) {
  __shared__ __align__(16) float bufA[32 * CSTR], bufB[32 * CSTR];
  __shared__ float4 wf1[16 * 3], wf2[32 * 17], wf3[16 * 33];
  __shared__ float  w41[2 * 16], w42[16 * 32], w43[32 * 16];
  __shared__ float  wt4[162];
  __shared__ float  sB1[16], sB2[32], sB3[16], sB4[2];

  int tid  = threadIdx.x;
  int tile = blockIdx.x, b = blockIdx.y;
  int ts   = tile * TILE;

  if (tid < 32) {                         // L1: oc<16, ic<2
    int oc = tid >> 1, ic = tid & 1, a = oc * 10 + ic * 5;
    wf1[oc * 3 + ic] = make_float4(W1[a], W1[a+1], W1[a+2], W1[a+3]);
    w41[ic * 16 + oc] = W1[a + 4];
  }
  for (int pr = tid; pr < 512; pr += 256) {   // L2: oc<32, ic<16
    int oc = pr >> 4, ic = pr & 15, a = oc * 80 + ic * 5;
    wf2[oc * 17 + ic] = make_float4(W2[a], W2[a+1], W2[a+2], W2[a+3]);
    w42[ic * 32 + oc] = W2[a + 4];
  }
  for (int pr = tid; pr < 512; pr += 256) {   // L3: oc<16, ic<32
    int oc = pr >> 5, ic = pr & 31, a = oc * 160 + ic * 5;
    wf3[oc * 33 + ic] = make_float4(W3[a], W3[a+1], W3[a+2], W3[a+3]);
    w43[ic * 16 + oc] = W3[a + 4];
  }
  for (int i = tid; i < 160; i += 256) wt4[(i / 80) * 81 + i % 80] = W4[i];
  if (tid < 16)       sB1[tid]      = Bs1[tid];
  else if (tid < 48)  sB2[tid - 16] = Bs2[tid - 16];
  else if (tid < 64)  sB3[tid - 48] = Bs3[tid - 48];
  else if (tid < 66)  sB4[tid - 64] = Bs4[tid - 64];

  for (int i = tid; i < 2 * CSTR; i += 256) {
    int c = i >= CSTR, col = i - c * CSTR;
    int g = ts + col - 10;
    bufA[c * CSTR + col] = (g >= 0 && g < G) ? h[(b * 2 + c) * G + g] : 0.f;
  }
  __syncthreads();

  conv4<2, 16, 3>(bufA, bufB, wf1, w41, sB1, tid);     // 256 thr
  __syncthreads();
  conv8<16, 32, 17>(bufB, bufA, wf2, w42, sB2, tid);   // 256 thr
  __syncthreads();
  conv4<32, 16, 33>(bufA, bufB, wf3, w43, sB3, tid);   // 256 thr
  __syncthreads();

  if (tid < 96) {
    int oc = tid >= 48;
    int j  = tid - oc * 48;
    int i  = 10 + j;
    float sacc = sB4[oc];
    #pragma unroll
    for (int ic = 0; ic < 16; ++ic) {
      const float* ip = bufB + ic * CSTR + i - 2;
      #pragma unroll
      for (int k = 0; k < 5; ++k)
        sacc = fmaf(ip[k], wt4[oc * 81 + ic * 5 + k], sacc);
    }
    int gp = ts + j;
    if (gp < G) {
      if (oc == 0) {
        yg[(b * 2 + 0) * G + gp] = sacc;
      } else {
        float sp_ = fmaxf(sacc, 0.f) + log1pf(__expf(-fabsf(sacc)));
        yg[(b * 2 + 1) * G + gp] = sp_;
      }
    }
  }
}

// ---------------------------------------------------------------------------
// Kernel C v7 (r15 best): packed-f32 Gaussian recurrence, 2 t/lane.
// ---------------------------------------------------------------------------
__global__ __launch_bounds__(512) void k_pred(
    const float* __restrict__ xt, const float* __restrict__ yt,
    const float* __restrict__ ls_rho, const float* __restrict__ yg,
    float* __restrict__ out) {
  __shared__ float4 sp[512];              // {y0[2j], y1[2j], y0[2j+1], y1[2j+1]}
  __shared__ float pA0[512], pA1[512], pB0[512], pB1[512];
  __shared__ float red[8];

  int tid = threadIdx.x;
  int b = blockIdx.y, tile = blockIdx.x;
  float ls = ls_rho[0];
  float s  = sqrtf(0.5f * LOG2E) / ls;
  float dl = s * (4.4f / 999.f);

  const float* y0 = yg + (b * 2 + 0) * G;
  const float* y1 = yg + (b * 2 + 1) * G;
  {
    int g0 = 2 * tid, g1 = 2 * tid + 1;
    float a0 = (g0 < G) ? y0[g0] : 0.f, b0_ = (g0 < G) ? y1[g0] : 0.f;
    float a1 = (g1 < G) ? y0[g1] : 0.f, b1_ = (g1 < G) ? y1[g1] : 0.f;
    sp[tid] = make_float4(a0, b0_, a1, b1_);
  }
  __syncthreads();

  int lane = tid & 63, wv = tid >> 6;     // wv = g-slice 0..7 (128 g each)
  int ta = tile * 128 + lane;
  float ua = s * xt[b * NT + ta];
  float ub = s * xt[b * NT + ta + 64];
  float base = 2.2f * s - dl * (float)(wv * 128);
  float aa = ua + base, ab = ub + base;
  float r = EXP2F(-2.f * dl * dl);
  f32x2 Wab = {EXP2F(64.f - aa * aa), EXP2F(64.f - ab * ab)};
  f32x2 qab = {EXP2F(dl * (aa + aa) - dl * dl), EXP2F(dl * (ab + ab) - dl * dl)};
  const f32x2 R2 = {r, r};

  f32x2 accA = (f32x2)0.f, accB = (f32x2)0.f;   // (mu, sg)
  const float4* p = sp + wv * 64;
  #pragma unroll 4
  for (int i = 0; i < 64; ++i) {
    float4 v = p[i];
    f32x2 v01 = {v.x, v.y};
    f32x2 v23 = {v.z, v.w};
    accA = PKFMA(SPLAT_LO(Wab), v01, accA);
    accB = PKFMA(SPLAT_HI(Wab), v01, accB);
    Wab *= qab; qab *= R2;
    accA = PKFMA(SPLAT_LO(Wab), v23, accA);
    accB = PKFMA(SPLAT_HI(Wab), v23, accB);
    Wab *= qab; qab *= R2;
  }
  pA0[tid] = accA.x; pA1[tid] = accA.y; pB0[tid] = accB.x; pB1[tid] = accB.y;
  __syncthreads();

  float lp = 0.f;
  if (tid < 128) {
    int which = tid >> 6, l = tid & 63;
    int t = tile * 128 + which * 64 + l;
    const float* q0 = which ? pB0 : pA0;
    const float* q1 = which ? pB1 : pA1;
    float mu = 0.f, sg = 0.f;
    #pragma unroll
    for (int k = 0; k < 8; ++k) { mu += q0[l + 64 * k]; sg += q1[l + 64 * k]; }
    mu *= 0x1p-64f;
    sg *= 0x1p-64f;
    out[b * NT + t]      = mu;
    out[BN + b * NT + t] = sg;
    float z = (yt[b * NT + t] - mu) / sg;
    lp = -0.5f * z * z - __logf(sg) - 0.5f * LN2PI;
  }
  #pragma unroll
  for (int m = 32; m; m >>= 1) lp += __shfl_xor(lp, m);
  if ((tid & 63) == 0) red[tid >> 6] = lp;
  __syncthreads();
  if (tid == 0) {
    float tot = 0.f;
    #pragma unroll
    for (int i = 0; i < 8; ++i) tot += red[i];
    atomicAdd(out + 2 * BN, -tot * (1.f / (float)NT));
  }
}

extern "C" void kernel_launch(void* const* d_in, const int* in_sizes, int n_in,
                              void* d_out, int out_size, void* d_ws, size_t ws_size,
                              hipStream_t stream) {
  const float* xc  = (const float*)d_in[0];
  const float* yc  = (const float*)d_in[1];
  const float* xt  = (const float*)d_in[2];
  const float* yt  = (const float*)d_in[3];
  const float* lsx = (const float*)d_in[4];
  const float* lsr = (const float*)d_in[5];
  const float* W1  = (const float*)d_in[6];  const float* b1 = (const float*)d_in[7];
  const float* W2  = (const float*)d_in[8];  const float* b2 = (const float*)d_in[9];
  const float* W3  = (const float*)d_in[10]; const float* b3 = (const float*)d_in[11];
  const float* W4  = (const float*)d_in[12]; const float* b4 = (const float*)d_in[13];

  float* out = (float*)d_out;
  float* h   = (float*)d_ws;        // B*2*G
  float* yg  = h + B * 2 * G;       // B*2*G

  k_smooth<<<dim3(16, B), 512, 0, stream>>>(xc, yc, lsx, h, out + 2 * BN);
  k_conv<<<dim3(NTILE, B), 256, 0, stream>>>(h, W1, b1, W2, b2, W3, b3, W4, b4, yg);
  k_pred<<<dim3(16, B), 512, 0, stream>>>(xt, yt, lsr, yg, out);
}